// Round 4
// baseline (380.917 us; speedup 1.0000x reference)
//
#include <hip/hip_runtime.h>

#define NN 8192
#define FF 64
#define NOUT 64
#define KS 32             // K-split: grid = 64 mtiles * 32 = 2048 blocks, 4/CU resident
#define KCHUNK (NN / KS)  // 256

typedef __bf16 bf16x8 __attribute__((ext_vector_type(8)));
typedef float f32x4 __attribute__((ext_vector_type(4)));

__device__ inline bf16x8 cvt8(float4 a, float4 b) {
    bf16x8 r;
    r[0] = (__bf16)a.x; r[1] = (__bf16)a.y; r[2] = (__bf16)a.z; r[3] = (__bf16)a.w;
    r[4] = (__bf16)b.x; r[5] = (__bf16)b.y; r[6] = (__bf16)b.z; r[7] = (__bf16)b.w;
    return r;
}

// features [8192][64] f32 -> featT [64][8192] bf16, coalesced via LDS tile.
__global__ __launch_bounds__(256)
void transpose_kernel(const float* __restrict__ feat, __bf16* __restrict__ featT) {
    __shared__ __bf16 t[64][72];
    int tid = threadIdx.x, blk = blockIdx.x; // 128 blocks, 64 feat-rows each
    int r = tid >> 2, c0 = (tid & 3) * 16;
    const float* p = feat + (size_t)(blk * 64 + r) * FF + c0;
    float4 v0 = *(const float4*)(p);
    float4 v1 = *(const float4*)(p + 4);
    float4 v2 = *(const float4*)(p + 8);
    float4 v3 = *(const float4*)(p + 12);
    #pragma unroll
    for (int j = 0; j < 4; ++j) {
        t[c0 + 0 + j][r]  = (__bf16)(&v0.x)[j];
        t[c0 + 4 + j][r]  = (__bf16)(&v1.x)[j];
        t[c0 + 8 + j][r]  = (__bf16)(&v2.x)[j];
        t[c0 + 12 + j][r] = (__bf16)(&v3.x)[j];
    }
    __syncthreads();
    int n = tid >> 2, co = (tid & 3) * 16;
    __bf16* dst = featT + (size_t)n * NN + blk * 64 + co;
    *(bf16x8*)dst       = *(const bf16x8*)&t[n][co];
    *(bf16x8*)(dst + 8) = *(const bf16x8*)&t[n][co + 8];
}

// adj streamed once, barrier-free K-loop: featT slice staged to LDS ONCE,
// then pure adj float4 stream + ds_read B-frags + MFMA. Deg via ones-col MFMA.
__global__ __launch_bounds__(256, 4)
void main_kernel(const float* __restrict__ adj, const __bf16* __restrict__ featT,
                 __bf16* __restrict__ partN, float* __restrict__ partDeg) {
    __shared__ __bf16 bt[64][264];   // [n][k] slice, stride 264 el = 528B (4-bank row adv)
    int tid = threadIdx.x;
    int w = tid >> 6, lane = tid & 63, ln = lane & 15, q = lane >> 4;
    int ks = blockIdx.x & (KS - 1);
    int mt = blockIdx.x >> 5;        // 64 m-tiles of 128 rows

    // ---- one-time featT slice stage: [64 n][256 k] bf16 (32 KB) ----
    {
        int n = tid >> 2, kb = (tid & 3) * 64;
        const __bf16* src = featT + (size_t)n * NN + ks * KCHUNK + kb;
        #pragma unroll
        for (int i = 0; i < 8; ++i)
            *(bf16x8*)&bt[n][kb + i * 8] = *(const bf16x8*)(src + i * 8);
    }
    __syncthreads();    // the ONLY barrier

    int rowA = mt * 128 + w * 32 + ln;
    const float* ap0 = adj + (size_t)rowA * NN + ks * KCHUNK + q * 8;
    const float* ap1 = ap0 + (size_t)16 * NN;

    f32x4 acc[2][4], accd[2];
    #pragma unroll
    for (int f = 0; f < 2; ++f) {
        accd[f] = 0;
        #pragma unroll
        for (int t = 0; t < 4; ++t) acc[f][t] = 0;
    }

    bf16x8 ones;
    __bf16 o = (ln == 0) ? (__bf16)1.0f : (__bf16)0.0f;
    #pragma unroll
    for (int i = 0; i < 8; ++i) ones[i] = o;

    #pragma unroll 4
    for (int s = 0; s < KCHUNK / 32; ++s) {   // 8 iters, no barriers: loads pipeline freely
        float4 a0 = *(const float4*)(ap0);
        float4 a1 = *(const float4*)(ap0 + 4);
        float4 a2 = *(const float4*)(ap1);
        float4 a3 = *(const float4*)(ap1 + 4);
        bf16x8 b0 = *(const bf16x8*)&bt[ln][s * 32 + q * 8];
        bf16x8 b1 = *(const bf16x8*)&bt[ln + 16][s * 32 + q * 8];
        bf16x8 b2 = *(const bf16x8*)&bt[ln + 32][s * 32 + q * 8];
        bf16x8 b3 = *(const bf16x8*)&bt[ln + 48][s * 32 + q * 8];
        bf16x8 af0 = cvt8(a0, a1);
        bf16x8 af1 = cvt8(a2, a3);
        acc[0][0] = __builtin_amdgcn_mfma_f32_16x16x32_bf16(af0, b0, acc[0][0], 0, 0, 0);
        acc[1][0] = __builtin_amdgcn_mfma_f32_16x16x32_bf16(af1, b0, acc[1][0], 0, 0, 0);
        acc[0][1] = __builtin_amdgcn_mfma_f32_16x16x32_bf16(af0, b1, acc[0][1], 0, 0, 0);
        acc[1][1] = __builtin_amdgcn_mfma_f32_16x16x32_bf16(af1, b1, acc[1][1], 0, 0, 0);
        acc[0][2] = __builtin_amdgcn_mfma_f32_16x16x32_bf16(af0, b2, acc[0][2], 0, 0, 0);
        acc[1][2] = __builtin_amdgcn_mfma_f32_16x16x32_bf16(af1, b2, acc[1][2], 0, 0, 0);
        acc[0][3] = __builtin_amdgcn_mfma_f32_16x16x32_bf16(af0, b3, acc[0][3], 0, 0, 0);
        acc[1][3] = __builtin_amdgcn_mfma_f32_16x16x32_bf16(af1, b3, acc[1][3], 0, 0, 0);
        accd[0] = __builtin_amdgcn_mfma_f32_16x16x32_bf16(af0, ones, accd[0], 0, 0, 0);
        accd[1] = __builtin_amdgcn_mfma_f32_16x16x32_bf16(af1, ones, accd[1], 0, 0, 0);
        ap0 += 32; ap1 += 32;
    }

    // C/D layout: col = ln, row(within 16-tile) = q*4 + r
    #pragma unroll
    for (int f = 0; f < 2; ++f) {
        int grow = mt * 128 + w * 32 + f * 16 + q * 4;
        #pragma unroll
        for (int r = 0; r < 4; ++r) {
            size_t base = ((size_t)(ks << 13) + grow + r) * FF + ln;
            partN[base +  0] = (__bf16)acc[f][0][r];
            partN[base + 16] = (__bf16)acc[f][1][r];
            partN[base + 32] = (__bf16)acc[f][2][r];
            partN[base + 48] = (__bf16)acc[f][3][r];
        }
        if (ln == 0) {
            #pragma unroll
            for (int r = 0; r < 4; ++r)
                partDeg[(ks << 13) + grow + r] = accd[f][r];
        }
    }
}

// out = [feat | (sum_ks partN)/(sum_ks partDeg + 1)] @ W^T  via bf16 MFMA
__global__ __launch_bounds__(256)
void epilogue_kernel(const float* __restrict__ feat, const float* __restrict__ W,
                     const __bf16* __restrict__ partN, const float* __restrict__ partDeg,
                     float* __restrict__ out) {
    __shared__ __bf16 dataB[64][136];
    __shared__ float rdeg[64];
    int tid = threadIdx.x, blk = blockIdx.x;

    if (tid < 64) {
        float s = 0.f;
        #pragma unroll
        for (int ks = 0; ks < KS; ++ks) s += partDeg[(ks << 13) + blk * 64 + tid];
        rdeg[tid] = 1.0f / (s + 1.0f);
    }
    __syncthreads();

    #pragma unroll
    for (int i = 0; i < 2; ++i) {
        int idx = tid + i * 256;
        int r = idx >> 3, c = (idx & 7) * 8;
        float s[8];
        #pragma unroll
        for (int j = 0; j < 8; ++j) s[j] = 0.f;
        #pragma unroll
        for (int ks = 0; ks < KS; ++ks) {
            bf16x8 v = *(const bf16x8*)&partN[((size_t)(ks << 13) + blk * 64 + r) * FF + c];
            #pragma unroll
            for (int j = 0; j < 8; ++j) s[j] += (float)v[j];
        }
        float rd = rdeg[r];
        bf16x8 o;
        #pragma unroll
        for (int j = 0; j < 8; ++j) o[j] = (__bf16)(s[j] * rd);
        *(bf16x8*)&dataB[r][64 + c] = o;
    }
    #pragma unroll
    for (int i = 0; i < 2; ++i) {
        int idx = tid + i * 256;
        int r = idx >> 3, c = (idx & 7) * 8;
        const float* p = feat + (size_t)(blk * 64 + r) * FF + c;
        float4 f0 = *(const float4*)p;
        float4 f1 = *(const float4*)(p + 4);
        *(bf16x8*)&dataB[r][c] = cvt8(f0, f1);
    }
    __syncthreads();

    int w = tid >> 6, lane = tid & 63, ln = lane & 15, q = lane >> 4;
    f32x4 acc[4];
    #pragma unroll
    for (int t = 0; t < 4; ++t) acc[t] = 0;

    #pragma unroll
    for (int kk = 0; kk < 4; ++kk) {
        bf16x8 af = *(const bf16x8*)&dataB[w * 16 + ln][kk * 32 + q * 8];
        #pragma unroll
        for (int t = 0; t < 4; ++t) {
            const float* wp = W + (size_t)(t * 16 + ln) * 128 + kk * 32 + q * 8;
            float4 b0 = *(const float4*)wp;
            float4 b1 = *(const float4*)(wp + 4);
            bf16x8 bf = cvt8(b0, b1);
            acc[t] = __builtin_amdgcn_mfma_f32_16x16x32_bf16(af, bf, acc[t], 0, 0, 0);
        }
    }

    int grow = blk * 64 + w * 16 + q * 4;
    #pragma unroll
    for (int t = 0; t < 4; ++t)
        #pragma unroll
        for (int r = 0; r < 4; ++r)
            out[(size_t)(grow + r) * NOUT + t * 16 + ln] = acc[t][r];
}

extern "C" void kernel_launch(void* const* d_in, const int* in_sizes, int n_in,
                              void* d_out, int out_size, void* d_ws, size_t ws_size,
                              hipStream_t stream) {
    const float* adj  = (const float*)d_in[0];
    const float* feat = (const float*)d_in[1];
    const float* W    = (const float*)d_in[2];
    float* out = (float*)d_out;
    char* ws = (char*)d_ws;

    // ws: featT 1MB | partN 32MB (KS*8192*64 bf16) | partDeg 1MB
    __bf16* featT   = (__bf16*)ws;
    __bf16* partN   = (__bf16*)(ws + (1 << 20));
    float*  partDeg = (float*)(ws + (1 << 20) + (size_t)KS * NN * FF * 2);

    transpose_kernel<<<NN / 64, 256, 0, stream>>>(feat, featT);
    main_kernel<<<(NN / 128) * KS, 256, 0, stream>>>(adj, featT, partN, partDeg);
    epilogue_kernel<<<NN / 64, 256, 0, stream>>>(feat, W, partN, partDeg, out);
}

// Round 5
// 376.748 us; speedup vs baseline: 1.0111x; 1.0111x over previous
//
#include <hip/hip_runtime.h>

#define NN 8192
#define FF 64
#define NOUT 64
#define KS 16              // K-split: grid = 64 mtiles * 16 = 1024 blocks, 2/CU resident
#define KCHUNK (NN / KS)   // 512
#define PAD 8
#define BSTRIDE (KCHUNK + PAD)   // 520 el rows: 16B-aligned, b128 reads at quad floor

typedef __bf16 bf16x8 __attribute__((ext_vector_type(8)));
typedef float f32x4 __attribute__((ext_vector_type(4)));

__device__ inline bf16x8 cvt8(float4 a, float4 b) {
    bf16x8 r;
    r[0] = (__bf16)a.x; r[1] = (__bf16)a.y; r[2] = (__bf16)a.z; r[3] = (__bf16)a.w;
    r[4] = (__bf16)b.x; r[5] = (__bf16)b.y; r[6] = (__bf16)b.z; r[7] = (__bf16)b.w;
    return r;
}

// adj streamed once. Self-contained: block transposes its own feat k-slice into
// LDS (bt[n][k] bf16), then barrier-free K-loop: adj float4 stream + ds_read
// B-frags + 10 MFMA. Rowsum(adj) via ones-col-0 B-frag MFMAs (free).
__global__ __launch_bounds__(256, 2)
void main_kernel(const float* __restrict__ adj, const float* __restrict__ feat,
                 __bf16* __restrict__ partN, float* __restrict__ partDeg) {
    __shared__ __bf16 bt[64][BSTRIDE];   // 65 KB: featT slice [n][k]
    int tid = threadIdx.x;
    int w = tid >> 6, lane = tid & 63, ln = lane & 15, q = lane >> 4;
    int ks = blockIdx.x & (KS - 1);      // ks = blk&15, XCD = blk%8 -> feat slice L2-local
    int mt = blockIdx.x >> 4;            // 64 m-tiles of 128 rows

    // ---- stage feat[ks*512 .. +512)[64] fp32 -> bt[64 n][512 k] bf16 ----
    {
        int r = tid >> 2, cg = (tid & 3) * 16;   // 64 rows x 4 col-groups per chunk
        const float* fb = feat + ((size_t)ks * KCHUNK + r) * FF + cg;
        #pragma unroll
        for (int kb = 0; kb < 8; ++kb) {         // 8 chunks of 64 k-rows
            const float* p = fb + (size_t)kb * 64 * FF;
            float4 v0 = *(const float4*)(p);
            float4 v1 = *(const float4*)(p + 4);
            float4 v2 = *(const float4*)(p + 8);
            float4 v3 = *(const float4*)(p + 12);
            int kk = kb * 64 + r;
            #pragma unroll
            for (int j = 0; j < 4; ++j) {
                bt[cg + 0 + j][kk]  = (__bf16)(&v0.x)[j];
                bt[cg + 4 + j][kk]  = (__bf16)(&v1.x)[j];
                bt[cg + 8 + j][kk]  = (__bf16)(&v2.x)[j];
                bt[cg + 12 + j][kk] = (__bf16)(&v3.x)[j];
            }
        }
    }
    __syncthreads();    // the ONLY barrier

    int rowA = mt * 128 + w * 32 + ln;
    const float* ap0 = adj + (size_t)rowA * NN + ks * KCHUNK + q * 8;
    const float* ap1 = ap0 + (size_t)16 * NN;

    f32x4 acc[2][4], accd[2];
    #pragma unroll
    for (int f = 0; f < 2; ++f) {
        accd[f] = 0;
        #pragma unroll
        for (int t = 0; t < 4; ++t) acc[f][t] = 0;
    }

    bf16x8 ones;
    __bf16 o = (ln == 0) ? (__bf16)1.0f : (__bf16)0.0f;
    #pragma unroll
    for (int i = 0; i < 8; ++i) ones[i] = o;

    #pragma unroll 4
    for (int s = 0; s < KCHUNK / 32; ++s) {   // 16 iters, barrier-free
        float4 a0 = *(const float4*)(ap0);
        float4 a1 = *(const float4*)(ap0 + 4);
        float4 a2 = *(const float4*)(ap1);
        float4 a3 = *(const float4*)(ap1 + 4);
        bf16x8 b0 = *(const bf16x8*)&bt[ln][s * 32 + q * 8];
        bf16x8 b1 = *(const bf16x8*)&bt[ln + 16][s * 32 + q * 8];
        bf16x8 b2 = *(const bf16x8*)&bt[ln + 32][s * 32 + q * 8];
        bf16x8 b3 = *(const bf16x8*)&bt[ln + 48][s * 32 + q * 8];
        bf16x8 af0 = cvt8(a0, a1);
        bf16x8 af1 = cvt8(a2, a3);
        acc[0][0] = __builtin_amdgcn_mfma_f32_16x16x32_bf16(af0, b0, acc[0][0], 0, 0, 0);
        acc[1][0] = __builtin_amdgcn_mfma_f32_16x16x32_bf16(af1, b0, acc[1][0], 0, 0, 0);
        acc[0][1] = __builtin_amdgcn_mfma_f32_16x16x32_bf16(af0, b1, acc[0][1], 0, 0, 0);
        acc[1][1] = __builtin_amdgcn_mfma_f32_16x16x32_bf16(af1, b1, acc[1][1], 0, 0, 0);
        acc[0][2] = __builtin_amdgcn_mfma_f32_16x16x32_bf16(af0, b2, acc[0][2], 0, 0, 0);
        acc[1][2] = __builtin_amdgcn_mfma_f32_16x16x32_bf16(af1, b2, acc[1][2], 0, 0, 0);
        acc[0][3] = __builtin_amdgcn_mfma_f32_16x16x32_bf16(af0, b3, acc[0][3], 0, 0, 0);
        acc[1][3] = __builtin_amdgcn_mfma_f32_16x16x32_bf16(af1, b3, acc[1][3], 0, 0, 0);
        accd[0] = __builtin_amdgcn_mfma_f32_16x16x32_bf16(af0, ones, accd[0], 0, 0, 0);
        accd[1] = __builtin_amdgcn_mfma_f32_16x16x32_bf16(af1, ones, accd[1], 0, 0, 0);
        ap0 += 32; ap1 += 32;
    }

    // C/D layout: col = ln, row(within 16-tile) = q*4 + r
    #pragma unroll
    for (int f = 0; f < 2; ++f) {
        int grow = mt * 128 + w * 32 + f * 16 + q * 4;
        #pragma unroll
        for (int r = 0; r < 4; ++r) {
            size_t base = ((size_t)(ks << 13) + grow + r) * FF + ln;
            partN[base +  0] = (__bf16)acc[f][0][r];
            partN[base + 16] = (__bf16)acc[f][1][r];
            partN[base + 32] = (__bf16)acc[f][2][r];
            partN[base + 48] = (__bf16)acc[f][3][r];
        }
        if (ln == 0) {
            #pragma unroll
            for (int r = 0; r < 4; ++r)
                partDeg[(ks << 13) + grow + r] = accd[f][r];
        }
    }
}

// out = [feat | (sum_ks partN)/(sum_ks partDeg + 1)] @ W^T  via bf16 MFMA
__global__ __launch_bounds__(256)
void epilogue_kernel(const float* __restrict__ feat, const float* __restrict__ W,
                     const __bf16* __restrict__ partN, const float* __restrict__ partDeg,
                     float* __restrict__ out) {
    __shared__ __bf16 dataB[64][136];
    __shared__ float rdeg[64];
    int tid = threadIdx.x, blk = blockIdx.x;

    if (tid < 64) {
        float s = 0.f;
        #pragma unroll
        for (int ks = 0; ks < KS; ++ks) s += partDeg[(ks << 13) + blk * 64 + tid];
        rdeg[tid] = 1.0f / (s + 1.0f);
    }
    __syncthreads();

    #pragma unroll
    for (int i = 0; i < 2; ++i) {
        int idx = tid + i * 256;
        int r = idx >> 3, c = (idx & 7) * 8;
        float s[8];
        #pragma unroll
        for (int j = 0; j < 8; ++j) s[j] = 0.f;
        #pragma unroll
        for (int ks = 0; ks < KS; ++ks) {
            bf16x8 v = *(const bf16x8*)&partN[((size_t)(ks << 13) + blk * 64 + r) * FF + c];
            #pragma unroll
            for (int j = 0; j < 8; ++j) s[j] += (float)v[j];
        }
        float rd = rdeg[r];
        bf16x8 o;
        #pragma unroll
        for (int j = 0; j < 8; ++j) o[j] = (__bf16)(s[j] * rd);
        *(bf16x8*)&dataB[r][64 + c] = o;
    }
    #pragma unroll
    for (int i = 0; i < 2; ++i) {
        int idx = tid + i * 256;
        int r = idx >> 3, c = (idx & 7) * 8;
        const float* p = feat + (size_t)(blk * 64 + r) * FF + c;
        float4 f0 = *(const float4*)p;
        float4 f1 = *(const float4*)(p + 4);
        *(bf16x8*)&dataB[r][c] = cvt8(f0, f1);
    }
    __syncthreads();

    int w = tid >> 6, lane = tid & 63, ln = lane & 15, q = lane >> 4;
    f32x4 acc[4];
    #pragma unroll
    for (int t = 0; t < 4; ++t) acc[t] = 0;

    #pragma unroll
    for (int kk = 0; kk < 4; ++kk) {
        bf16x8 af = *(const bf16x8*)&dataB[w * 16 + ln][kk * 32 + q * 8];
        #pragma unroll
        for (int t = 0; t < 4; ++t) {
            const float* wp = W + (size_t)(t * 16 + ln) * 128 + kk * 32 + q * 8;
            float4 b0 = *(const float4*)wp;
            float4 b1 = *(const float4*)(wp + 4);
            bf16x8 bf = cvt8(b0, b1);
            acc[t] = __builtin_amdgcn_mfma_f32_16x16x32_bf16(af, bf, acc[t], 0, 0, 0);
        }
    }

    int grow = blk * 64 + w * 16 + q * 4;
    #pragma unroll
    for (int t = 0; t < 4; ++t)
        #pragma unroll
        for (int r = 0; r < 4; ++r)
            out[(size_t)(grow + r) * NOUT + t * 16 + ln] = acc[t][r];
}

extern "C" void kernel_launch(void* const* d_in, const int* in_sizes, int n_in,
                              void* d_out, int out_size, void* d_ws, size_t ws_size,
                              hipStream_t stream) {
    const float* adj  = (const float*)d_in[0];
    const float* feat = (const float*)d_in[1];
    const float* W    = (const float*)d_in[2];
    float* out = (float*)d_out;
    char* ws = (char*)d_ws;

    // ws: partN 16MB (KS*8192*64 bf16) | partDeg 512KB
    __bf16* partN   = (__bf16*)ws;
    float*  partDeg = (float*)(ws + (size_t)KS * NN * FF * 2);

    main_kernel<<<(NN / 128) * KS, 256, 0, stream>>>(adj, feat, partN, partDeg);
    epilogue_kernel<<<NN / 64, 256, 0, stream>>>(feat, W, partN, partDeg, out);
}